// Round 1
// baseline (277.446 us; speedup 1.0000x reference)
//
#include <hip/hip_runtime.h>

// g2[b,c,h,w] = sum_d cost[b,d,h,w] * h1[b,c,h,w+d]   (w+d < W, else 0)
// B=4 C=32 H=256 W=512 D=48, fp32.
//
// Block = (b, h, w-half): stages h1[b, :, h, wstart..wstart+311] into LDS
// (zero past W). NT=256 = 4 waves; wave = 8-channel group; lane owns 4
// consecutive w (w0 = lane*4) -> every ds_read_b128 is 16B/lane contiguous
// across the wave = conflict-free.
//
// v2 changes vs v1 (was latency/spill-bound: VGPR=64 with ~115 live values
// => scratch spills; VALUBusy 20%, HBM 19%):
//   - no register sliding window: h1 operands re-read from LDS per group
//     (2x ds_read_b128 per channel per group). Loop-carried state = acc only.
//   - cost loads explicitly prefetched distance-2 via 3 rotating register
//     buffers; the whole 12-group main loop is statically unrolled so all
//     buffer indices are compile-time (no scratch).
//   - first two cost buffers issued BEFORE __syncthreads so their HBM
//     latency hides under the staging drain.

#define BB 4
#define CC 32
#define HH 256
#define WW 512
#define DDISP 48
#define HW (HH * WW)     // 131072
#define TW 256
#define WROW 312         // 303 needed (TW-4 + 44 + 7), quad-rounded + pad
#define NT 256

__global__ __launch_bounds__(NT, 4)
void dense_warp_kernel(const float* __restrict__ h1,
                       const float* __restrict__ cost,
                       float* __restrict__ out)
{
    __shared__ float h1s[CC * WROW];   // 39936 B -> 4 blocks/CU

    const int blk    = blockIdx.x;
    const int wside  = blk & 1;
    const int h      = (blk >> 1) & (HH - 1);
    const int b      = blk >> 9;
    const int wstart = wside * TW;
    const int tid    = threadIdx.x;

    const int lane = tid & 63;
    const int wid  = tid >> 6;        // 0..3 -> channel group
    const int c0   = wid << 3;        // 8 channels per wave
    const int w0   = lane << 2;       // 4 consecutive w per lane

    const float* cp = cost + ((size_t)b * DDISP * HH + (size_t)h) * WW + wstart + w0;

    // 3 rotating cost buffers: group g uses cv{g%3}; prefetch distance 2.
    float cv0[4][4], cv1[4][4], cv2[4][4];

#define LOADCV(buf, g) do {                                                    \
    _Pragma("unroll")                                                          \
    for (int dd = 0; dd < 4; ++dd) {                                           \
        float4 t = *(const float4*)(cp + (size_t)(4 * (g) + dd) * HW);         \
        buf[dd][0] = t.x; buf[dd][1] = t.y;                                    \
        buf[dd][2] = t.z; buf[dd][3] = t.w;                                    \
    }                                                                          \
} while (0)

    // Issue the first two groups' cost loads before the barrier: their HBM
    // latency hides under the staging loads + the barrier's vmcnt(0) drain.
    LOADCV(cv0, 0);
    LOADCV(cv1, 1);

    // ---- stage h1[b, :, h, wstart .. wstart+311] into LDS (zeros past W) ----
    {
        const float* src = h1 + ((size_t)b * CC * HH + (size_t)h) * WW;
        for (int idx = tid; idx < CC * 78; idx += NT) {   // 78 quads/row
            int r    = idx / 78;
            int q    = idx - r * 78;
            int col  = q << 2;
            int wsrc = wstart + col;
            float4 v = make_float4(0.f, 0.f, 0.f, 0.f);
            if (wsrc < WW) v = *(const float4*)(src + (size_t)r * HW + wsrc);
            *(float4*)(&h1s[r * WROW + col]) = v;
        }
    }
    __syncthreads();

    float acc[8][4];
#pragma unroll
    for (int c = 0; c < 8; ++c)
#pragma unroll
        for (int j = 0; j < 4; ++j) acc[c][j] = 0.f;

    const float* lbase = &h1s[c0 * WROW + w0];

    // Group g covers d = 4g..4g+3. For output j (0..3), operand index is
    // w0 + 4g + (dd+j), dd+j in 0..6 -> two quads [4g, 4g+7] per channel.
#define DO_GROUP(buf, g) do {                                                  \
    _Pragma("unroll")                                                          \
    for (int c = 0; c < 8; ++c) {                                              \
        const float* lp = lbase + c * WROW + 4 * (g);                          \
        float4 q0 = *(const float4*)(lp);                                      \
        float4 q1 = *(const float4*)(lp + 4);                                  \
        float srcv[8] = { q0.x, q0.y, q0.z, q0.w, q1.x, q1.y, q1.z, q1.w };    \
        _Pragma("unroll")                                                      \
        for (int dd = 0; dd < 4; ++dd)                                         \
            _Pragma("unroll")                                                  \
            for (int j = 0; j < 4; ++j)                                        \
                acc[c][j] += buf[dd][j] * srcv[dd + j];                        \
    }                                                                          \
} while (0)

    // Fully static schedule: before computing group g, issue loads for g+2.
    LOADCV(cv2,  2);  DO_GROUP(cv0,  0);
    LOADCV(cv0,  3);  DO_GROUP(cv1,  1);
    LOADCV(cv1,  4);  DO_GROUP(cv2,  2);
    LOADCV(cv2,  5);  DO_GROUP(cv0,  3);
    LOADCV(cv0,  6);  DO_GROUP(cv1,  4);
    LOADCV(cv1,  7);  DO_GROUP(cv2,  5);
    LOADCV(cv2,  8);  DO_GROUP(cv0,  6);
    LOADCV(cv0,  9);  DO_GROUP(cv1,  7);
    LOADCV(cv1, 10);  DO_GROUP(cv2,  8);
    LOADCV(cv2, 11);  DO_GROUP(cv0,  9);
                      DO_GROUP(cv1, 10);
                      DO_GROUP(cv2, 11);

#undef LOADCV
#undef DO_GROUP

    float* outBase = out + ((size_t)b * CC * HH + (size_t)h) * WW + wstart + w0;
#pragma unroll
    for (int c = 0; c < 8; ++c) {
        float* op = outBase + (size_t)(c0 + c) * HW;
        *(float4*)op = make_float4(acc[c][0], acc[c][1], acc[c][2], acc[c][3]);
    }
}

extern "C" void kernel_launch(void* const* d_in, const int* in_sizes, int n_in,
                              void* d_out, int out_size, void* d_ws, size_t ws_size,
                              hipStream_t stream) {
    const float* h1   = (const float*)d_in[0];
    const float* cost = (const float*)d_in[1];
    float* out        = (float*)d_out;
    dim3 grid(BB * HH * 2);   // (b, h, w-half)
    dense_warp_kernel<<<grid, NT, 0, stream>>>(h1, cost, out);
}

// Round 2
// 242.942 us; speedup vs baseline: 1.1420x; 1.1420x over previous
//
#include <hip/hip_runtime.h>

// g2[b,c,h,w] = sum_d cost[b,d,h,w] * h1[b,c,h,w+d]   (w+d < W, else 0)
// B=4 C=32 H=256 W=512 D=48, fp32.
//
// v3: designed FOR the 64-VGPR occupancy cliff (m69: waves/CU halves at
// vgpr=64). v1/v2 both spilled (loop-carried state 96-112 floats vs 64
// regs; v2's WRITE_SIZE showed +170MB scratch traffic).
//
//   - 16 channels per block (was 32): LDS 19968 B -> 8 blocks/CU ->
//     32 waves/CU (was 16). Latency hiding via TLP, not ILP.
//   - wave = 4 channels, lane = 4 consecutive w. Loop-carried regs:
//     acc[4][4]=16 + cv[4][4]=16 + addressing ~= 50 < 64. Zero spill.
//   - no register sliding window: h1 re-read from LDS, 2x ds_read_b128
//     per channel per group (16B/lane contiguous = conflict-free).
//   - group loop held at unroll 1 so the scheduler can't hoist all 48
//     cost loads and recreate v2's spill.

#define BB 4
#define CC 32
#define CHB 16           // channels per block
#define HH 256
#define WW 512
#define DDISP 48
#define HW (HH * WW)     // 131072
#define TW 256
#define WROW 312         // 303 needed (TW-4 + 44 + 7), quad-rounded + pad
#define NT 256

__global__ __launch_bounds__(NT, 8)
void dense_warp_kernel(const float* __restrict__ h1,
                       const float* __restrict__ cost,
                       float* __restrict__ out)
{
    __shared__ float h1s[CHB * WROW];   // 19968 B -> 8 blocks/CU

    const int blk    = blockIdx.x;
    const int wside  = blk & 1;
    const int h      = (blk >> 1) & (HH - 1);
    const int chalf  = (blk >> 9) & 1;
    const int b      = blk >> 10;
    const int wstart = wside * TW;
    const int tid    = threadIdx.x;

    // ---- stage h1[b, chalf*16 .. +15, h, wstart .. wstart+311] (zeros past W)
    {
        const float* src = h1 + (((size_t)b * CC + chalf * CHB) * HH + (size_t)h) * WW;
        for (int idx = tid; idx < CHB * 78; idx += NT) {   // 78 quads/row
            int r    = idx / 78;
            int q    = idx - r * 78;
            int col  = q << 2;
            int wsrc = wstart + col;
            float4 v = make_float4(0.f, 0.f, 0.f, 0.f);
            if (wsrc < WW) v = *(const float4*)(src + (size_t)r * HW + wsrc);
            *(float4*)(&h1s[r * WROW + col]) = v;
        }
    }
    __syncthreads();

    const int lane = tid & 63;
    const int wid  = tid >> 6;        // 0..3 -> channel group within block
    const int c0   = wid << 2;        // 4 channels per wave
    const int w0   = lane << 2;       // 4 consecutive w per lane

    float acc[4][4];
#pragma unroll
    for (int c = 0; c < 4; ++c)
#pragma unroll
        for (int j = 0; j < 4; ++j) acc[c][j] = 0.f;

    const float* lbase = &h1s[c0 * WROW + w0];
    const float* cpg   = cost + ((size_t)b * DDISP * HH + (size_t)h) * WW + wstart + w0;

    // Group g covers d = 4g..4g+3. For output j (0..3), operand index is
    // w0 + 4g + (dd+j), dd+j in 0..6 -> two LDS quads [4g, 4g+7] per channel.
#pragma unroll 1
    for (int g = 0; g < 12; ++g) {
        float cv[4][4];
#pragma unroll
        for (int dd = 0; dd < 4; ++dd) {
            float4 t = *(const float4*)(cpg + (size_t)dd * HW);
            cv[dd][0] = t.x; cv[dd][1] = t.y; cv[dd][2] = t.z; cv[dd][3] = t.w;
        }
        cpg += (size_t)4 * HW;

#pragma unroll
        for (int c = 0; c < 4; ++c) {
            const float* lp = lbase + c * WROW;
            float4 q0 = *(const float4*)(lp);
            float4 q1 = *(const float4*)(lp + 4);
            float srcv[8] = { q0.x, q0.y, q0.z, q0.w, q1.x, q1.y, q1.z, q1.w };
#pragma unroll
            for (int dd = 0; dd < 4; ++dd)
#pragma unroll
                for (int j = 0; j < 4; ++j)
                    acc[c][j] += cv[dd][j] * srcv[dd + j];
        }
        lbase += 4;   // window slides one quad per group
    }

    float* outBase = out + (((size_t)b * CC + chalf * CHB) * HH + (size_t)h) * WW
                     + wstart + w0;
#pragma unroll
    for (int c = 0; c < 4; ++c) {
        float* op = outBase + (size_t)(c0 + c) * HW;
        *(float4*)op = make_float4(acc[c][0], acc[c][1], acc[c][2], acc[c][3]);
    }
}

extern "C" void kernel_launch(void* const* d_in, const int* in_sizes, int n_in,
                              void* d_out, int out_size, void* d_ws, size_t ws_size,
                              hipStream_t stream) {
    const float* h1   = (const float*)d_in[0];
    const float* cost = (const float*)d_in[1];
    float* out        = (float*)d_out;
    dim3 grid(BB * HH * 2 * 2);   // (b, chalf, h, w-half)
    dense_warp_kernel<<<grid, NT, 0, stream>>>(h1, cost, out);
}